// Round 1
// baseline (555.653 us; speedup 1.0000x reference)
//
#include <hip/hip_runtime.h>

// Problem constants (match reference setup_inputs)
constexpr int   B_   = 8;
constexpr int   RES  = 160;
constexpr long long GCELLS = (long long)B_ * RES * RES * RES;   // 32,768,000
constexpr float EMA  = 0.95f;
constexpr float THRE = 0.01f;

// Pass 1: per-point scatter. scratch[lin] = atomicMax over (float_bits(val)+1).
// val >= 0, so uint compare of float bits is monotone; +1 makes 0 a clean
// "untouched" sentinel and is reversible bitwise (s-1).
__global__ void __launch_bounds__(256)
occ_scatter_kernel(const float* __restrict__ pts,
                   const int*   __restrict__ bidx,
                   const float* __restrict__ val,
                   unsigned int* __restrict__ scratch,
                   int n) {
    int i = blockIdx.x * blockDim.x + threadIdx.x;
    if (i >= n) return;

    float px = pts[3 * i + 0];
    float py = pts[3 * i + 1];
    float pz = pts[3 * i + 2];

    // Match jnp: ((p / 2 + 0.5) * res).astype(int32), clamped to [0, res-1].
    int gx = (int)((px / 2.0f + 0.5f) * (float)RES);
    int gy = (int)((py / 2.0f + 0.5f) * (float)RES);
    int gz = (int)((pz / 2.0f + 0.5f) * (float)RES);
    gx = min(max(gx, 0), RES - 1);
    gy = min(max(gy, 0), RES - 1);
    gz = min(max(gz, 0), RES - 1);

    int b = bidx[i];
    int lin = ((b * RES + gx) * RES + gy) * RES + gz;   // < 2^31, int ok

    unsigned int u = __float_as_uint(val[i]) + 1u;
    atomicMax(&scratch[lin], u);
}

// Pass 2: per-cell finalize, float4-vectorized.
// out_occ currently holds scratch bits; overwrite in place with 0/1 mask.
__global__ void __launch_bounds__(256)
occ_finalize_kernel(const float* __restrict__ grid,
                    float* __restrict__ out_val,
                    float* __restrict__ out_occ) {
    long long i = (long long)blockIdx.x * blockDim.x + threadIdx.x;  // one float4 per thread
    if (i >= GCELLS / 4) return;

    float4 g = ((const float4*)grid)[i];
    uint4  s = ((const uint4*)out_occ)[i];

    float4 r;
    r.x = s.x ? fmaxf(g.x * EMA, __uint_as_float(s.x - 1u)) : g.x;
    r.y = s.y ? fmaxf(g.y * EMA, __uint_as_float(s.y - 1u)) : g.y;
    r.z = s.z ? fmaxf(g.z * EMA, __uint_as_float(s.z - 1u)) : g.z;
    r.w = s.w ? fmaxf(g.w * EMA, __uint_as_float(s.w - 1u)) : g.w;

    float4 o;
    o.x = (r.x > THRE) ? 1.0f : 0.0f;
    o.y = (r.y > THRE) ? 1.0f : 0.0f;
    o.z = (r.z > THRE) ? 1.0f : 0.0f;
    o.w = (r.w > THRE) ? 1.0f : 0.0f;

    ((float4*)out_val)[i] = r;
    ((float4*)out_occ)[i] = o;
}

extern "C" void kernel_launch(void* const* d_in, const int* in_sizes, int n_in,
                              void* d_out, int out_size, void* d_ws, size_t ws_size,
                              hipStream_t stream) {
    const float* grid = (const float*)d_in[0];   // (B,R,R,R) fp32
    const float* pts  = (const float*)d_in[1];   // (N,3) fp32
    const int*   bidx = (const int*)d_in[2];     // (N,) int32
    const float* val  = (const float*)d_in[3];   // (N,) fp32

    float* out_val = (float*)d_out;              // first G floats: new grid
    float* out_occ = out_val + GCELLS;           // second G floats: occupancy mask

    int n = in_sizes[1] / 3;                     // N points

    // Zero the scratch/occ region (doubles as atomic-max scratch).
    hipMemsetAsync(out_occ, 0, (size_t)GCELLS * sizeof(float), stream);

    int blocks_pts = (n + 255) / 256;
    occ_scatter_kernel<<<blocks_pts, 256, 0, stream>>>(
        pts, bidx, val, (unsigned int*)out_occ, n);

    long long quads = GCELLS / 4;                // G divisible by 4
    int blocks_cells = (int)((quads + 255) / 256);
    occ_finalize_kernel<<<blocks_cells, 256, 0, stream>>>(grid, out_val, out_occ);
}